// Round 5
// baseline (202.262 us; speedup 1.0000x reference)
//
#include <hip/hip_runtime.h>

// B=2, N=64, D=256, H=8, DK=32.  ROWS = B*N*N = 8192.
#define ROWS 8192
#define DIM  256

typedef short short8 __attribute__((ext_vector_type(8)));
typedef float f4     __attribute__((ext_vector_type(4)));

__device__ __forceinline__ float bf2f(unsigned int u16) {
    union { unsigned int i; float f; } v;
    v.i = (u16 & 0xffffu) << 16;
    return v.f;
}
__device__ __forceinline__ unsigned short f2bf(float f) {
    union { float f; unsigned int u; } v; v.f = f;
    unsigned int r = v.u + 0x7fffu + ((v.u >> 16) & 1u);   // RNE
    return (unsigned short)(r >> 16);
}

// ---------------------------------------------------------------------------
// Merged casts. Blocks [0,2048): x(8192x256 fp32)->xb bf16.
// Blocks [2048,2624): weights -> WT[n][k] bf16 packed.
//   w0..w4 at w*65536 ; W1(256x512)->512x256 @327680 ; W2(512x256)->256x512 @458752
// ---------------------------------------------------------------------------
__global__ __launch_bounds__(256)
void cast_all(const float* __restrict__ x, unsigned short* __restrict__ xb,
              const float* __restrict__ w0, const float* __restrict__ w1,
              const float* __restrict__ w2, const float* __restrict__ w3,
              const float* __restrict__ w4, const float* __restrict__ w5,
              const float* __restrict__ w6, unsigned short* __restrict__ wt)
{
    if (blockIdx.x < 2048) {
        const size_t i = ((size_t)blockIdx.x * 256 + threadIdx.x) * 4;
        float4 v = *(const float4*)(x + i);
        uint2 p;
        p.x = f2bf(v.x) | ((unsigned int)f2bf(v.y) << 16);
        p.y = f2bf(v.z) | ((unsigned int)f2bf(v.w) << 16);
        *(uint2*)(xb + i) = p;
        return;
    }
    __shared__ float t[32][33];
    int id = blockIdx.x - 2048;
    const float* src; int K, N, Ntiles; size_t doff;
    if (id < 320) {
        int w = id >> 6; id &= 63; K = 256; N = 256; Ntiles = 8;
        doff = (size_t)w * 65536;
        src = (w == 0) ? w0 : (w == 1) ? w1 : (w == 2) ? w2 : (w == 3) ? w3 : w4;
    } else if (id < 448) {
        id -= 320; K = 256; N = 512; Ntiles = 16; doff = 327680; src = w5;
    } else {
        id -= 448; K = 512; N = 256; Ntiles = 8;  doff = 458752; src = w6;
    }
    const int tk = id / Ntiles, tn = id % Ntiles;
    const int k0 = tk * 32, n0 = tn * 32;
    const int c = threadIdx.x & 31, r8 = threadIdx.x >> 5;
    for (int rr = r8; rr < 32; rr += 8)
        t[rr][c] = src[(size_t)(k0 + rr) * N + n0 + c];
    __syncthreads();
    for (int rr = r8; rr < 32; rr += 8)
        wt[doff + (size_t)(n0 + rr) * K + k0 + c] = f2bf(t[c][rr]);
}

// ---------------------------------------------------------------------------
// Projection MFMA GEMM with head-major scatter epilogue.
//   wsel 0 (lk): dst[b][h][x=i][a=j][d]   wsel 1 (rk): dst[b][h][a=i][y=j][d]
//   wsel 2 (lv): dst[b][h][x=i][a=j][d]   wsel 3 (rv): dst[b][h][y=j][a=i][d]
// grid = (16, 64)
// ---------------------------------------------------------------------------
__global__ __launch_bounds__(256)
void proj_mfma(const unsigned short* __restrict__ A, const unsigned short* __restrict__ WT,
               unsigned short* __restrict__ projT)
{
    const int lane = threadIdx.x & 63, wave = threadIdx.x >> 6;
    const int wsel = blockIdx.x >> 2;
    const int col0 = (blockIdx.x & 3) * 64;
    const int m0 = blockIdx.y * 128 + wave * 32;
    const int lm = lane & 15, lk8 = (lane >> 4) * 8;
    const unsigned short* W = WT + (size_t)wsel * 65536;
    unsigned short* dst = projT + (size_t)wsel * 2097152;

    f4 acc[2][4];
    #pragma unroll
    for (int i = 0; i < 2; ++i)
        #pragma unroll
        for (int j = 0; j < 4; ++j) acc[i][j] = (f4){0.f, 0.f, 0.f, 0.f};

    for (int kc = 0; kc < 256; kc += 32) {
        short8 af[2], bf[4];
        #pragma unroll
        for (int i = 0; i < 2; ++i)
            af[i] = *(const short8*)(A + (size_t)(m0 + i * 16 + lm) * 256 + kc + lk8);
        #pragma unroll
        for (int j = 0; j < 4; ++j)
            bf[j] = *(const short8*)(W + (size_t)(col0 + j * 16 + lm) * 256 + kc + lk8);
        #pragma unroll
        for (int i = 0; i < 2; ++i)
            #pragma unroll
            for (int j = 0; j < 4; ++j)
                acc[i][j] = __builtin_amdgcn_mfma_f32_16x16x32_bf16(af[i], bf[j], acc[i][j], 0, 0, 0);
    }

    const int rbase = (lane >> 4) * 4;
    const int swap = (wsel == 3);
    #pragma unroll
    for (int i = 0; i < 2; ++i)
        #pragma unroll
        for (int j = 0; j < 4; ++j) {
            const int c = col0 + j * 16 + lm;
            const int h = c >> 5, d = c & 31;
            #pragma unroll
            for (int r = 0; r < 4; ++r) {
                const int m = m0 + i * 16 + rbase + r;
                const int b = m >> 12, ii = (m >> 6) & 63, jj = m & 63;
                const int p = swap ? jj : ii;
                const int q = swap ? ii : jj;
                const size_t idx = ((((size_t)b * 8 + h) * 64 + p) * 64 + q) * 32 + d;
                dst[idx] = f2bf(acc[i][j][r]);
            }
        }
}

// ---------------------------------------------------------------------------
// Fused triangle attention (scores + softmax + aggregation), block per (b,h,x).
// lkT/lvT: [b][h][x][a][d], rkT: [b][h][a][y][d], rvT: [b][h][y][a][d]
// obuf[(b*64+x)*64+y][h*32+d] bf16.  grid = 1024, 256 thr.
// ---------------------------------------------------------------------------
__global__ __launch_bounds__(256)
void attn_fused(const unsigned short* __restrict__ lkT, const unsigned short* __restrict__ rkT,
                const unsigned short* __restrict__ lvT, const unsigned short* __restrict__ rvT,
                unsigned short* __restrict__ obuf)
{
    __shared__ float att[64][64];           // [a][y]
    __shared__ float lkx[64][32];
    __shared__ float lvL[64][32];
    __shared__ float smx[4][64], ssm[4][64], invL[64];
    const int bi = blockIdx.x;
    const int b = bi >> 9, h = (bi >> 6) & 7, x = bi & 63;
    const size_t bh = (size_t)b * 8 + h;
    const int tid = threadIdx.x;

    {   // stage lk[x], lv[x] (contiguous 4KB each)
        const int a = tid >> 2, d0 = (tid & 3) * 8;
        const size_t off = ((bh * 64 + x) * 64 + a) * 32 + d0;
        uint4 pk = *(const uint4*)(lkT + off);
        lkx[a][d0 + 0] = bf2f(pk.x); lkx[a][d0 + 1] = bf2f(pk.x >> 16);
        lkx[a][d0 + 2] = bf2f(pk.y); lkx[a][d0 + 3] = bf2f(pk.y >> 16);
        lkx[a][d0 + 4] = bf2f(pk.z); lkx[a][d0 + 5] = bf2f(pk.z >> 16);
        lkx[a][d0 + 6] = bf2f(pk.w); lkx[a][d0 + 7] = bf2f(pk.w >> 16);
        uint4 qk = *(const uint4*)(lvT + off);
        lvL[a][d0 + 0] = bf2f(qk.x); lvL[a][d0 + 1] = bf2f(qk.x >> 16);
        lvL[a][d0 + 2] = bf2f(qk.y); lvL[a][d0 + 3] = bf2f(qk.y >> 16);
        lvL[a][d0 + 4] = bf2f(qk.z); lvL[a][d0 + 5] = bf2f(qk.z >> 16);
        lvL[a][d0 + 6] = bf2f(qk.w); lvL[a][d0 + 7] = bf2f(qk.w >> 16);
    }
    __syncthreads();

    {   // scores + per-slice max
        const int y = tid & 63, az = tid >> 6;
        float mx = -1e30f;
        for (int a = az; a < 64; a += 4) {
            const unsigned short* rp = rkT + ((bh * 64 + a) * 64 + y) * 32;
            float acc = 0.f;
            #pragma unroll
            for (int t = 0; t < 4; ++t) {
                uint4 pk = *(const uint4*)(rp + t * 8);
                acc += lkx[a][t*8 + 0] * bf2f(pk.x) + lkx[a][t*8 + 1] * bf2f(pk.x >> 16)
                     + lkx[a][t*8 + 2] * bf2f(pk.y) + lkx[a][t*8 + 3] * bf2f(pk.y >> 16)
                     + lkx[a][t*8 + 4] * bf2f(pk.z) + lkx[a][t*8 + 5] * bf2f(pk.z >> 16)
                     + lkx[a][t*8 + 6] * bf2f(pk.w) + lkx[a][t*8 + 7] * bf2f(pk.w >> 16);
            }
            float v = acc * 0.17677669529663687f;
            att[a][y] = v;
            mx = fmaxf(mx, v);
        }
        smx[az][y] = mx;
    }
    __syncthreads();

    {   // exp + partial sums
        const int y = tid & 63, az = tid >> 6;
        const float mx = fmaxf(fmaxf(smx[0][y], smx[1][y]), fmaxf(smx[2][y], smx[3][y]));
        float s = 0.f;
        for (int a = az; a < 64; a += 4) {
            float e = __expf(att[a][y] - mx);
            att[a][y] = e;
            s += e;
        }
        ssm[az][y] = s;
    }
    __syncthreads();
    if (tid < 64)
        invL[tid] = 1.f / (ssm[0][tid] + ssm[1][tid] + ssm[2][tid] + ssm[3][tid]);
    __syncthreads();

    {   // aggregation
        const int dp = tid & 15, yb = tid >> 4;
        #pragma unroll
        for (int it = 0; it < 4; ++it) {
            const int y = yb + it * 16;
            const unsigned short* rvr = rvT + (bh * 64 + y) * 2048 + dp * 2;
            float a0 = 0.f, a1 = 0.f;
            #pragma unroll 8
            for (int a = 0; a < 64; ++a) {
                unsigned int pk = *(const unsigned int*)(rvr + a * 32);
                float w = att[a][y];
                a0 += w * lvL[a][2 * dp]     * bf2f(pk);
                a1 += w * lvL[a][2 * dp + 1] * bf2f(pk >> 16);
            }
            const float inv = invL[y];
            a0 *= inv; a1 *= inv;
            unsigned int st = f2bf(a0) | ((unsigned int)f2bf(a1) << 16);
            *(unsigned int*)(obuf + (((size_t)b * 64 + x) * 64 + y) * 256 + h * 32 + dp * 2) = st;
        }
    }
}

// ---------------------------------------------------------------------------
// Generic MFMA GEMM (FFN1): out = relu( A(MxK bf16) @ WT(NxK)^T + bias ), bf16 out
// tile 128x64, grid = (N/64, M/128)
// ---------------------------------------------------------------------------
__global__ __launch_bounds__(256)
void gemm_mfma(const unsigned short* __restrict__ A, const unsigned short* __restrict__ WT,
               const float* __restrict__ bias, unsigned short* __restrict__ outB,
               int K, int N)
{
    const int lane = threadIdx.x & 63, wave = threadIdx.x >> 6;
    const int m0 = blockIdx.y * 128 + wave * 32;
    const int col0 = blockIdx.x * 64;
    const int lm = lane & 15, lk8 = (lane >> 4) * 8;

    f4 acc[2][4];
    #pragma unroll
    for (int i = 0; i < 2; ++i)
        #pragma unroll
        for (int j = 0; j < 4; ++j) acc[i][j] = (f4){0.f, 0.f, 0.f, 0.f};

    for (int kc = 0; kc < K; kc += 32) {
        short8 af[2], bf[4];
        #pragma unroll
        for (int i = 0; i < 2; ++i)
            af[i] = *(const short8*)(A + (size_t)(m0 + i * 16 + lm) * K + kc + lk8);
        #pragma unroll
        for (int j = 0; j < 4; ++j)
            bf[j] = *(const short8*)(WT + (size_t)(col0 + j * 16 + lm) * K + kc + lk8);
        #pragma unroll
        for (int i = 0; i < 2; ++i)
            #pragma unroll
            for (int j = 0; j < 4; ++j)
                acc[i][j] = __builtin_amdgcn_mfma_f32_16x16x32_bf16(af[i], bf[j], acc[i][j], 0, 0, 0);
    }

    const int rbase = (lane >> 4) * 4;
    #pragma unroll
    for (int i = 0; i < 2; ++i)
        #pragma unroll
        for (int j = 0; j < 4; ++j) {
            const int n = col0 + j * 16 + lm;
            const float bb = bias[n];
            #pragma unroll
            for (int r = 0; r < 4; ++r) {
                const int m = m0 + i * 16 + rbase + r;
                outB[(size_t)m * N + n] = f2bf(fmaxf(acc[i][j][r] + bb, 0.f));
            }
        }
}

// ---------------------------------------------------------------------------
// Fused GEMM + residual + LayerNorm. N = 256 (full rows in-block).
// tile: 16 rows x 256 cols; 4 waves, wave w covers cols w*64..+63.
//   t = A @ WT^T [+ bias] + resid ;  out = LN(t) * gamma + beta
// mode 0: write outF (fp32) and outB (bf16).  mode 1: write outF only.
// grid = 512 (8192/16), 256 thr.
// ---------------------------------------------------------------------------
__global__ __launch_bounds__(256)
void gemm_ln(const unsigned short* __restrict__ A, const unsigned short* __restrict__ WT,
             const float* __restrict__ bias, const float* __restrict__ resid,
             const float* __restrict__ gamma, const float* __restrict__ beta,
             float* __restrict__ outF, unsigned short* __restrict__ outB,
             int K, int mode)
{
    __shared__ float ps[16][4], pq[16][4];
    const int lane = threadIdx.x & 63, wave = threadIdx.x >> 6;
    const int m0 = blockIdx.x * 16;
    const int col0 = wave * 64;
    const int lm = lane & 15, lk8 = (lane >> 4) * 8;

    f4 acc[4];
    #pragma unroll
    for (int j = 0; j < 4; ++j) acc[j] = (f4){0.f, 0.f, 0.f, 0.f};

    for (int kc = 0; kc < K; kc += 32) {
        short8 af = *(const short8*)(A + (size_t)(m0 + lm) * K + kc + lk8);
        #pragma unroll
        for (int j = 0; j < 4; ++j) {
            short8 bf = *(const short8*)(WT + (size_t)(col0 + j * 16 + lm) * K + kc + lk8);
            acc[j] = __builtin_amdgcn_mfma_f32_16x16x32_bf16(af, bf, acc[j], 0, 0, 0);
        }
    }

    // v[j][r] = acc + bias + resid ; per-(row r) partial sums over j
    const int rbase = (lane >> 4) * 4;
    float v[4][4];
    float s[4] = {0.f, 0.f, 0.f, 0.f}, q[4] = {0.f, 0.f, 0.f, 0.f};
    #pragma unroll
    for (int j = 0; j < 4; ++j) {
        const int n = col0 + j * 16 + lm;
        const float bb = bias ? bias[n] : 0.f;
        #pragma unroll
        for (int r = 0; r < 4; ++r) {
            const int m = m0 + rbase + r;
            float t = acc[j][r] + bb + resid[(size_t)m * 256 + n];
            v[j][r] = t;
            s[r] += t;
            q[r] += t * t;
        }
    }
    // reduce over the 16 lanes of the quad (bits 0..3 of lane id)
    #pragma unroll
    for (int off = 1; off < 16; off <<= 1) {
        #pragma unroll
        for (int r = 0; r < 4; ++r) {
            s[r] += __shfl_xor(s[r], off);
            q[r] += __shfl_xor(q[r], off);
        }
    }
    if (lm == 0) {
        #pragma unroll
        for (int r = 0; r < 4; ++r) {
            ps[rbase + r][wave] = s[r];
            pq[rbase + r][wave] = q[r];
        }
    }
    __syncthreads();
    #pragma unroll
    for (int r = 0; r < 4; ++r) {
        const int lr = rbase + r;
        const float S = ps[lr][0] + ps[lr][1] + ps[lr][2] + ps[lr][3];
        const float Q = pq[lr][0] + pq[lr][1] + pq[lr][2] + pq[lr][3];
        const float mu = S * (1.f / 256.f);
        const float ri = rsqrtf(Q * (1.f / 256.f) - mu * mu + 1e-5f);
        const int m = m0 + lr;
        #pragma unroll
        for (int j = 0; j < 4; ++j) {
            const int n = col0 + j * 16 + lm;
            const float rv = (v[j][r] - mu) * ri * gamma[n] + beta[n];
            outF[(size_t)m * 256 + n] = rv;
            if (mode == 0) outB[(size_t)m * 256 + n] = f2bf(rv);
        }
    }
}

// ---------------------------------------------------------------------------
extern "C" void kernel_launch(void* const* d_in, const int* in_sizes, int n_in,
                              void* d_out, int out_size, void* d_ws, size_t ws_size,
                              hipStream_t stream)
{
    const float* x    = (const float*)d_in[0];
    const float* Wlk  = (const float*)d_in[1];
    const float* Wrk  = (const float*)d_in[2];
    const float* Wlv  = (const float*)d_in[3];
    const float* Wrv  = (const float*)d_in[4];
    const float* Wout = (const float*)d_in[5];
    const float* g1   = (const float*)d_in[6];
    const float* be1  = (const float*)d_in[7];
    const float* W1   = (const float*)d_in[8];
    const float* b1   = (const float*)d_in[9];
    const float* W2   = (const float*)d_in[10];
    const float* b2   = (const float*)d_in[11];
    const float* g2   = (const float*)d_in[12];
    const float* be2  = (const float*)d_in[13];

    char* base = (char*)d_ws;
    const size_t MB = 1ull << 20;
    unsigned short* xb    = (unsigned short*)(base + 0);        // 4MB; reused as obuf
    unsigned short* obufb = (unsigned short*)(base + 0);
    unsigned short* projT = (unsigned short*)(base + 4 * MB);   // lkT,rkT,lvT,rvT 4x4MB
    unsigned short* lkT   = projT;
    unsigned short* rkT   = projT + 2097152;
    unsigned short* lvT   = projT + 2 * 2097152;
    unsigned short* rvT   = projT + 3 * 2097152;
    float*          hf    = (float*)(base + 20 * MB);           // 8MB
    unsigned short* hb    = (unsigned short*)(base + 28 * MB);  // 4MB
    unsigned short* midb  = (unsigned short*)(base + 36 * MB);  // 8MB
    unsigned short* WT    = (unsigned short*)(base + 52 * MB);  // 1.2MB

    // 1. casts (x -> bf16, weights -> transposed bf16)
    cast_all<<<2624, 256, 0, stream>>>(x, xb, Wlk, Wrk, Wlv, Wrv, Wout, W1, W2, WT);
    // 2. projections + head-major scatter
    proj_mfma<<<dim3(16, 64), 256, 0, stream>>>(xb, WT, projT);
    // 3. fused scores+softmax+aggregation -> obuf (bf16)
    attn_fused<<<1024, 256, 0, stream>>>(lkT, rkT, lvT, rvT, obufb);
    // 4. h = LN(x + obuf @ W_out) -> hf (fp32) + hb (bf16)
    gemm_ln<<<512, 256, 0, stream>>>(obufb, WT + 262144, nullptr, x, g1, be1, hf, hb, 256, 0);
    // 5. midb = relu(hb @ W1 + b1) (bf16)
    gemm_mfma<<<dim3(8, 64), 256, 0, stream>>>(hb, WT + 327680, b1, midb, 256, 512);
    // 6. out = LN(hf + midb @ W2 + b2) -> fp32 d_out
    gemm_ln<<<512, 256, 0, stream>>>(midb, WT + 458752, b2, hf, g2, be2, (float*)d_out, nullptr, 512, 1);
}